// Round 9
// baseline (5619.372 us; speedup 1.0000x reference)
//
#include <hip/hip_runtime.h>
#include <hip/hip_bf16.h>
#include <stdint.h>

typedef __hip_bfloat16 bf16;

__device__ __forceinline__ float us2f(uint16_t u){
  union { uint32_t i; float f; } v; v.i = ((uint32_t)u) << 16; return v.f;
}
__device__ __forceinline__ float bflo(uint32_t u){
  union { uint32_t i; float f; } v; v.i = u << 16; return v.f;
}
__device__ __forceinline__ float bfhi(uint32_t u){
  union { uint32_t i; float f; } v; v.i = u & 0xffff0000u; return v.f;
}
__device__ __forceinline__ uint16_t f2u16(float f){
  union { bf16 b; uint16_t u; } v; v.b = __float2bfloat16(f); return v.u;
}
// storage helpers: h buffers are float or bf16(uint16_t)
__device__ __forceinline__ float  ldh (const float* p, size_t i){ return p[i]; }
__device__ __forceinline__ float  ldh (const uint16_t* p, size_t i){ return us2f(p[i]); }
__device__ __forceinline__ float2 ldh2(const float* p, size_t i){ return ((const float2*)p)[i]; }
__device__ __forceinline__ float2 ldh2(const uint16_t* p, size_t i){
  uint32_t u = ((const uint32_t*)p)[i]; return make_float2(bflo(u), bfhi(u));
}
__device__ __forceinline__ void sth (float* p, size_t i, float v){ p[i] = v; }
__device__ __forceinline__ void sth (uint16_t* p, size_t i, float v){ p[i] = f2u16(v); }
__device__ __forceinline__ void sth2(float* p, size_t i, float2 v){ ((float2*)p)[i] = v; }
__device__ __forceinline__ void sth2(uint16_t* p, size_t i, float2 v){
  ((uint32_t*)p)[i] = (uint32_t)f2u16(v.x) | ((uint32_t)f2u16(v.y) << 16);
}

// ---------------- x-dtype detection (fp32 vs bf16) — safety net ----------------
__global__ void detect_kernel(const uint32_t* __restrict__ x, int* __restrict__ flag){
  int lane = threadIdx.x;
  uint32_t w = x[lane];
  uint32_t e = (w >> 7) & 0xffu;
  bool looks_bf16 = (e >= 118 && e <= 134);
  unsigned long long m = __ballot(looks_bf16);
  if (lane == 0) flag[0] = (__popcll(m) >= 32) ? 0 : 1;   // 1 = fp32 inputs
}

// ---------------- edge-dtype detection (int32 vs int64) — safety net ----------
__global__ void edetect_kernel(const uint32_t* __restrict__ ei, int* __restrict__ eflag){
  int lane = threadIdx.x;   // 64
  uint32_t w = ei[lane];
  bool ok = (lane & 1) ? (w == 0u) : true;
  unsigned long long m = __ballot(ok);
  if (lane == 0) eflag[0] = (__popcll(m) == 64) ? 1 : 0;  // 1 = int64 edges
}

// ---------------- params -> canonical fp32 copies ----------------
struct PP {
  const void* src[14];
  int off[14];
  int cnt[14];
};

__global__ void cvt_params_kernel(PP pp, float* __restrict__ dst, const int* __restrict__ flag){
  int b = blockIdx.x;
  int cnt = pp.cnt[b];
  float* d = dst + pp.off[b];
  if (flag[0] != 0){
    const float* s = (const float*)pp.src[b];
    for (int i = threadIdx.x; i < cnt; i += 256) d[i] = s[i];
  } else {
    const uint16_t* s = (const uint16_t*)pp.src[b];
    for (int i = threadIdx.x; i < cnt; i += 256) d[i] = us2f(s[i]);
  }
}

// ---------------- CSR build ----------------
__global__ void count_kernel(const int* __restrict__ ei, const int* __restrict__ eflag,
                             int* __restrict__ counts, int E, int n){
  int i = blockIdx.x * 256 + threadIdx.x;
  if (i >= E + n) return;
  int d;
  if (i < E) d = eflag[0] ? ei[2*(size_t)E + 2*(size_t)i] : ei[(size_t)E + i];
  else       d = i - E;
  atomicAdd(&counts[d], 1);
}

#define SCAN_BS 256
#define SCAN_CHUNK 1024

__global__ void scan1_kernel(const int* __restrict__ counts, int* __restrict__ offs,
                             int* __restrict__ bsums, int n){
  __shared__ int sdata[SCAN_BS];
  int b = blockIdx.x, t = threadIdx.x;
  int base = b * SCAN_CHUNK + t * 4;
  int v[4]; int s = 0;
  #pragma unroll
  for (int j=0;j<4;j++){ int idx = base+j; v[j] = (idx<n)? counts[idx] : 0; s += v[j]; }
  sdata[t] = s;
  __syncthreads();
  for (int off=1; off<SCAN_BS; off<<=1){
    int x = (t>=off)? sdata[t-off] : 0;
    __syncthreads();
    sdata[t] += x;
    __syncthreads();
  }
  int run = sdata[t] - s;
  #pragma unroll
  for (int j=0;j<4;j++){ int idx = base+j; if (idx<n) offs[idx] = run; run += v[j]; }
  if (t == SCAN_BS-1) bsums[b] = sdata[t];
}

__global__ void scan2_kernel(int* __restrict__ bsums, int nb){
  __shared__ int sdata[1024];
  int t = threadIdx.x;
  int v = (t<nb)? bsums[t] : 0;
  sdata[t] = v;
  __syncthreads();
  for (int off=1; off<1024; off<<=1){
    int x = (t>=off)? sdata[t-off] : 0;
    __syncthreads();
    sdata[t] += x;
    __syncthreads();
  }
  if (t<nb) bsums[t] = sdata[t] - v;
}

__global__ void scan3_kernel(int* __restrict__ offs, const int* __restrict__ bsums,
                             int* __restrict__ cursor, int n, int total){
  int i = blockIdx.x * 256 + threadIdx.x;
  if (i < n){
    int v = offs[i] + bsums[i / SCAN_CHUNK];
    offs[i] = v;
    cursor[i] = v;
  }
  if (i == n) offs[n] = total;
}

__global__ void fill_kernel(const int* __restrict__ ei, const int* __restrict__ eflag,
                            int* __restrict__ cursor, int* __restrict__ csr, int E, int n){
  int i = blockIdx.x * 256 + threadIdx.x;
  if (i >= E + n) return;
  int s, d;
  if (i < E){
    if (eflag[0]){ s = ei[2*(size_t)i]; d = ei[2*(size_t)E + 2*(size_t)i]; }
    else         { s = ei[i];           d = ei[(size_t)E + i]; }
  } else { s = i - E; d = i - E; }
  int pos = atomicAdd(&cursor[d], 1);
  csr[pos] = s;
}

// ---- GEMM: C[n,M] (TC) = A[n,K] @ W[K,M] (fp32 canonical), fp32 accum ----
// wave-parallel: 4 waves/block, 4 rows/wave, A broadcast via __shfl.
template<int K, int M, bool DET, typename TA, typename TC>
__global__ __launch_bounds__(256) void gemm_kernel(const void* __restrict__ Ap,
    const float* __restrict__ W, TC* __restrict__ C, int n, const int* __restrict__ flag){
  constexpr int CPL = M/64;
  constexpr int KC  = K/64;
  __shared__ float Ws[64*M];
  int t = threadIdx.x;
  int lane = t & 63;
  int r0 = blockIdx.x * 16 + (t >> 6) * 4;

  bool f32 = DET ? (flag[0] != 0) : false;
  const uint16_t* Au = (const uint16_t*)Ap;
  const float*    Af = (const float*)Ap;
  const TA*       At = (const TA*)Ap;

  float ar[4][KC];
  #pragma unroll
  for (int r=0;r<4;r++){
    int gr = r0 + r;
    #pragma unroll
    for (int j=0;j<KC;j++){
      size_t idx = (size_t)gr*K + j*64 + lane;
      float a = 0.f;
      if (gr < n){
        if (DET) a = f32 ? Af[idx] : us2f(Au[idx]);
        else     a = ldh(At, idx);
      }
      ar[r][j] = a;
    }
  }
  float acc[4][CPL];
  #pragma unroll
  for (int r=0;r<4;r++)
    #pragma unroll
    for (int j=0;j<CPL;j++) acc[r][j] = 0.f;

  for (int c=0; c<KC; c++){
    const float4* Wc4 = (const float4*)(W + (size_t)c*64*M);
    for (int i=t; i < 64*M/4; i += 256) ((float4*)Ws)[i] = Wc4[i];
    __syncthreads();
    #pragma unroll
    for (int k2=0; k2<64; k2++){
      float w[CPL];
      #pragma unroll
      for (int j=0;j<CPL;j++) w[j] = Ws[k2*M + j*64 + lane];
      #pragma unroll
      for (int r=0;r<4;r++){
        float a = __shfl(ar[r][c], k2);
        #pragma unroll
        for (int j=0;j<CPL;j++) acc[r][j] = fmaf(a, w[j], acc[r][j]);
      }
    }
    __syncthreads();
  }
  #pragma unroll
  for (int r=0;r<4;r++){
    int gr = r0 + r;
    if (gr < n){
      #pragma unroll
      for (int j=0;j<CPL;j++)
        sth(C, (size_t)gr*M + j*64 + lane, acc[r][j]);
    }
  }
}

// ---------------- per-node attention logits ----------------
template<int OUTD, int HD, typename T>
__global__ void logits_kernel(const T* __restrict__ hW, const float* __restrict__ a_src,
                              const float* __restrict__ a_dst, float* __restrict__ als,
                              float* __restrict__ ald, int n){
  int i = blockIdx.x * 256 + threadIdx.x;   // i = node*4 + h
  if (i >= n*4) return;
  int node = i >> 2, h = i & 3;
  const T* hp = hW + (size_t)node*OUTD + h*HD;
  float ss = 0.f, sd = 0.f;
  #pragma unroll
  for (int d2=0; d2<HD/2; d2++){
    float2 v = ldh2(hp, d2);
    int b = h*HD + 2*d2;
    ss += v.x*a_src[b] + v.y*a_src[b+1];
    sd += v.x*a_dst[b] + v.y*a_dst[b+1];
  }
  als[i] = ss; ald[i] = sd;
}

// ---------------- aggregation: one wave per destination node ----------------
// OUTD=128: lane owns dims {2*lane, 2*lane+1} (same head). OUTD=64: lane owns dim lane.
template<int OUTD, typename TIN, typename TOUT>
__global__ __launch_bounds__(256) void aggregate_kernel(const TIN* __restrict__ hW,
            const float* __restrict__ als, const float* __restrict__ ald,
            const int* __restrict__ offs, const int* __restrict__ csr,
            const float* __restrict__ bias, TOUT* __restrict__ hout, int n){
  int wid = (blockIdx.x * 256 + threadIdx.x) >> 6;   // node
  if (wid >= n) return;
  int lane = threadIdx.x & 63;
  int beg = offs[wid], end = offs[wid+1];
  const float4 ad = ((const float4*)ald)[wid];

  // pass A: per-head segment max (lanes parallel over edges)
  float m0=-1e30f, m1=-1e30f, m2=-1e30f, m3=-1e30f;
  for (int j = beg + lane; j < end; j += 64){
    int s = csr[j];
    float4 as = ((const float4*)als)[s];
    float e;
    e = as.x + ad.x; e = (e>0.f)? e : 0.2f*e; m0 = fmaxf(m0, e);
    e = as.y + ad.y; e = (e>0.f)? e : 0.2f*e; m1 = fmaxf(m1, e);
    e = as.z + ad.z; e = (e>0.f)? e : 0.2f*e; m2 = fmaxf(m2, e);
    e = as.w + ad.w; e = (e>0.f)? e : 0.2f*e; m3 = fmaxf(m3, e);
  }
  #pragma unroll
  for (int off=32; off>0; off>>=1){
    m0 = fmaxf(m0, __shfl_xor(m0, off));
    m1 = fmaxf(m1, __shfl_xor(m1, off));
    m2 = fmaxf(m2, __shfl_xor(m2, off));
    m3 = fmaxf(m3, __shfl_xor(m3, off));
  }

  int h = lane >> 4;
  float mh  = (h==0)? m0 : (h==1)? m1 : (h==2)? m2 : m3;
  float adh = (h==0)? ad.x : (h==1)? ad.y : (h==2)? ad.z : ad.w;

  if (OUTD == 128){
    float acc0 = 0.f, acc1 = 0.f, den = 0.f;
    for (int j=beg; j<end; j++){
      int s = csr[j];
      float e = als[s*4 + h] + adh;
      e = (e>0.f)? e : 0.2f*e;
      float ex = __expf(e - mh);
      den += ex;
      float2 hv = ldh2(hW, (size_t)s*64 + lane);
      acc0 = fmaf(ex, hv.x, acc0);
      acc1 = fmaf(ex, hv.y, acc1);
    }
    float inv = 1.f / (den + 1e-16f);
    float o0 = acc0*inv + bias[2*lane];
    float o1 = acc1*inv + bias[2*lane+1];
    o0 = (o0>0.f)? o0 : 0.f;
    o1 = (o1>0.f)? o1 : 0.f;
    sth2(hout, (size_t)wid*64 + lane, make_float2(o0, o1));
  } else {
    float acc0 = 0.f, den = 0.f;
    for (int j=beg; j<end; j++){
      int s = csr[j];
      float e = als[s*4 + h] + adh;
      e = (e>0.f)? e : 0.2f*e;
      float ex = __expf(e - mh);
      den += ex;
      acc0 = fmaf(ex, ldh(hW, (size_t)s*OUTD + lane), acc0);
    }
    float o0 = acc0 / (den + 1e-16f) + bias[lane];
    o0 = (o0>0.f)? o0 : 0.f;
    sth(hout, (size_t)wid*OUTD + lane, o0);
  }
}

// ---------- classifier: out[n,40] = h[n,64] @ Wc + bc  (FP32 output!) ----------
template<typename T>
__global__ __launch_bounds__(256) void classifier_kernel(const T* __restrict__ h,
      const float* __restrict__ Wc, const float* __restrict__ bc,
      float* __restrict__ out, int n){
  __shared__ float Ws[64*40 + 64];
  __shared__ float bs[40];
  int t = threadIdx.x;
  for (int i=t; i<64*40; i+=256) Ws[i] = Wc[i];
  if (t < 40) bs[t] = bc[t];
  for (int i = 64*40 + t; i < 64*40 + 64; i += 256) Ws[i] = 0.f; // pad
  __syncthreads();
  int wid = blockIdx.x * 4 + (t >> 6);
  if (wid >= n) return;
  int lane = t & 63;
  float a = ldh(h, (size_t)wid*64 + lane);
  float acc = 0.f;
  #pragma unroll
  for (int k=0;k<64;k++){
    float ak = __shfl(a, k);
    acc = fmaf(ak, Ws[k*40 + lane], acc);  // lanes >=40 hit pad (harmless)
  }
  if (lane < 40) out[(size_t)wid*40 + lane] = acc + bs[lane];
}

// ---------------- pipeline ----------------
template<typename TM, typename TO>
static void run_pipeline(void* const* d_in, int ei_idx, int pbase, int n, int E,
                         void* d_out, int out_size, void* d_ws, size_t ws_size,
                         hipStream_t stream){
  const void* x = d_in[0];
  const int* ei = (const int*)d_in[ei_idx];
  float* out = (float*)d_out;           // FP32 output (R8 sentinel evidence)
  int Etot = E + n;

  char* p = (char*)d_ws;
  auto alloc = [&](size_t bytes)->char* {
    char* r = p; p += (bytes + 255) & ~(size_t)255; return r;
  };
  int*   flag   = (int*)  alloc(256);
  int*   eflag  = (int*)  alloc(256);
  int*   counts = (int*)  alloc((size_t)n * 4);
  float* als    = (float*)alloc((size_t)n * 16);
  float* ald    = (float*)alloc((size_t)n * 16);
  float* prm    = (float*)alloc(48000 * 4);
  int*   cursor = counts;

  // csr/offs/bsums live in d_out (fp32: out_size*4 bytes = 16 MB; dead until
  // the final classifier fully overwrites it; same-stream ordering)
  size_t csr_b  = ((size_t)Etot * 4 + 255) & ~(size_t)255;
  size_t offs_b = ((size_t)(n + 1) * 4 + 255) & ~(size_t)255;
  size_t out_bytes = (size_t)out_size * 4;
  int *csr, *offs, *bsums;
  if (csr_b + offs_b + 4096 <= out_bytes){
    char* q = (char*)d_out;
    csr   = (int*)q;
    offs  = (int*)(q + csr_b);
    bsums = (int*)(q + csr_b + offs_b);
  } else {
    csr   = (int*)alloc((size_t)Etot * 4);
    offs  = (int*)alloc((size_t)(n + 1) * 4);
    bsums = (int*)alloc(4096);
  }
  TM* bufMid = (TM*)alloc((size_t)n * 128 * sizeof(TM));
  TO* bufOut = (TO*)alloc((size_t)n * 128 * sizeof(TO));

  PP pp;
  static const int cnts[14] = {16384,128,128,128, 16384,128,128,128, 8192,64,64,64, 2560,40};
  int off = 0;
  for (int i = 0; i < 14; i++){
    pp.src[i] = d_in[pbase + i];
    pp.cnt[i] = cnts[i];
    pp.off[i] = off;
    off += cnts[i];
  }
  const float* W0  = prm + pp.off[0];
  const float* as0 = prm + pp.off[1];
  const float* ad0 = prm + pp.off[2];
  const float* b0  = prm + pp.off[3];
  const float* W1  = prm + pp.off[4];
  const float* as1 = prm + pp.off[5];
  const float* ad1 = prm + pp.off[6];
  const float* b1  = prm + pp.off[7];
  const float* W2  = prm + pp.off[8];
  const float* as2 = prm + pp.off[9];
  const float* ad2 = prm + pp.off[10];
  const float* b2  = prm + pp.off[11];
  const float* Wc  = prm + pp.off[12];
  const float* bc  = prm + pp.off[13];

  hipMemsetAsync(counts, 0, (size_t)n * 4, stream);

  detect_kernel<<<1, 64, 0, stream>>>((const uint32_t*)x, flag);
  edetect_kernel<<<1, 64, 0, stream>>>((const uint32_t*)ei, eflag);
  cvt_params_kernel<<<14, 256, 0, stream>>>(pp, prm, flag);

  count_kernel<<<(Etot + 255)/256, 256, 0, stream>>>(ei, eflag, counts, E, n);
  int nb = (n + SCAN_CHUNK - 1) / SCAN_CHUNK;
  scan1_kernel<<<nb, SCAN_BS, 0, stream>>>(counts, offs, bsums, n);
  scan2_kernel<<<1, 1024, 0, stream>>>(bsums, nb);
  scan3_kernel<<<(n + 1 + 255)/256, 256, 0, stream>>>(offs, bsums, cursor, n, Etot);
  fill_kernel<<<(Etot + 255)/256, 256, 0, stream>>>(ei, eflag, cursor, csr, E, n);

  int gemm_grid = (n + 15) / 16;
  int log_grid  = (n*4 + 255) / 256;
  int agg_grid  = (n + 3) / 4;

  // layer 0: x -> bufMid -> bufOut   (x dtype runtime-detected; expect fp32)
  gemm_kernel<128,128,true,TO,TM><<<gemm_grid, 256, 0, stream>>>(x, W0, bufMid, n, flag);
  logits_kernel<128,32,TM><<<log_grid, 256, 0, stream>>>(bufMid, as0, ad0, als, ald, n);
  aggregate_kernel<128,TM,TO><<<agg_grid, 256, 0, stream>>>(bufMid, als, ald, offs, csr, b0, bufOut, n);

  // layer 1
  gemm_kernel<128,128,false,TO,TM><<<gemm_grid, 256, 0, stream>>>(bufOut, W1, bufMid, n, flag);
  logits_kernel<128,32,TM><<<log_grid, 256, 0, stream>>>(bufMid, as1, ad1, als, ald, n);
  aggregate_kernel<128,TM,TO><<<agg_grid, 256, 0, stream>>>(bufMid, als, ald, offs, csr, b1, bufOut, n);

  // layer 2 (outd=64)
  gemm_kernel<128,64,false,TO,TM><<<gemm_grid, 256, 0, stream>>>(bufOut, W2, bufMid, n, flag);
  logits_kernel<64,16,TM><<<log_grid, 256, 0, stream>>>(bufMid, as2, ad2, als, ald, n);
  aggregate_kernel<64,TM,TO><<<agg_grid, 256, 0, stream>>>(bufMid, als, ald, offs, csr, b2, bufOut, n);

  // classifier: fp32 writes, fully overwrites d_out (csr dead; same stream)
  classifier_kernel<TO><<<agg_grid, 256, 0, stream>>>(bufOut, Wc, bc, out, n);
}

// ---------------- launcher ----------------
extern "C" void kernel_launch(void* const* d_in, const int* in_sizes, int n_in,
                              void* d_out, int out_size, void* d_ws, size_t ws_size,
                              hipStream_t stream) {
  int n = in_sizes[0] / 128;

  int ei_idx, pbase;
  if (n_in >= 2 && in_sizes[1] > 1000000) { ei_idx = 1;        pbase = 2; }   // dict order
  else                                    { ei_idx = n_in - 1; pbase = 1; }   // signature order
  int E = in_sizes[ei_idx] / 2;

  size_t base = 512
              + (((size_t)n*4  + 255) & ~(size_t)255)
              + 2*(((size_t)n*16 + 255) & ~(size_t)255)
              + ((48000*4 + 255) & ~(size_t)255)
              + 65536;
  size_t f32buf  = ((size_t)n*128*4 + 255) & ~(size_t)255;
  size_t bf16buf = ((size_t)n*128*2 + 255) & ~(size_t)255;

  if (ws_size >= base + 2*f32buf)              // tier 1: ~107 MB, all fp32
    run_pipeline<float, float>(d_in, ei_idx, pbase, n, E, d_out, out_size, d_ws, ws_size, stream);
  else if (ws_size >= base + f32buf + bf16buf) // tier 2: ~81 MB, fp32 gather buf
    run_pipeline<float, uint16_t>(d_in, ei_idx, pbase, n, E, d_out, out_size, d_ws, ws_size, stream);
  else                                         // tier 3: ~55 MB, all bf16
    run_pipeline<uint16_t, uint16_t>(d_in, ei_idx, pbase, n, E, d_out, out_size, d_ws, ws_size, stream);
}

// Round 10
// 1270.882 us; speedup vs baseline: 4.4216x; 4.4216x over previous
//
#include <hip/hip_runtime.h>
#include <hip/hip_bf16.h>
#include <stdint.h>

typedef __hip_bfloat16 bf16;

__device__ __forceinline__ float us2f(uint16_t u){
  union { uint32_t i; float f; } v; v.i = ((uint32_t)u) << 16; return v.f;
}
__device__ __forceinline__ float bflo(uint32_t u){
  union { uint32_t i; float f; } v; v.i = u << 16; return v.f;
}
__device__ __forceinline__ float bfhi(uint32_t u){
  union { uint32_t i; float f; } v; v.i = u & 0xffff0000u; return v.f;
}
__device__ __forceinline__ uint16_t f2u16(float f){
  union { bf16 b; uint16_t u; } v; v.b = __float2bfloat16(f); return v.u;
}
// storage helpers: h buffers are float or bf16(uint16_t)
__device__ __forceinline__ float  ldh (const float* p, size_t i){ return p[i]; }
__device__ __forceinline__ float  ldh (const uint16_t* p, size_t i){ return us2f(p[i]); }
__device__ __forceinline__ float2 ldh2(const float* p, size_t i){ return ((const float2*)p)[i]; }
__device__ __forceinline__ float2 ldh2(const uint16_t* p, size_t i){
  uint32_t u = ((const uint32_t*)p)[i]; return make_float2(bflo(u), bfhi(u));
}
__device__ __forceinline__ void sth (float* p, size_t i, float v){ p[i] = v; }
__device__ __forceinline__ void sth (uint16_t* p, size_t i, float v){ p[i] = f2u16(v); }
__device__ __forceinline__ void sth2(float* p, size_t i, float2 v){ ((float2*)p)[i] = v; }
__device__ __forceinline__ void sth2(uint16_t* p, size_t i, float2 v){
  ((uint32_t*)p)[i] = (uint32_t)f2u16(v.x) | ((uint32_t)f2u16(v.y) << 16);
}

// ---------------- x-dtype detection (fp32 vs bf16) — safety net ----------------
__global__ void detect_kernel(const uint32_t* __restrict__ x, int* __restrict__ flag){
  int lane = threadIdx.x;
  uint32_t w = x[lane];
  uint32_t e = (w >> 7) & 0xffu;
  bool looks_bf16 = (e >= 118 && e <= 134);
  unsigned long long m = __ballot(looks_bf16);
  if (lane == 0) flag[0] = (__popcll(m) >= 32) ? 0 : 1;   // 1 = fp32 inputs
}

// ---------------- edge-dtype detection (int32 vs int64) — safety net ----------
__global__ void edetect_kernel(const uint32_t* __restrict__ ei, int* __restrict__ eflag){
  int lane = threadIdx.x;   // 64
  uint32_t w = ei[lane];
  bool ok = (lane & 1) ? (w == 0u) : true;
  unsigned long long m = __ballot(ok);
  if (lane == 0) eflag[0] = (__popcll(m) == 64) ? 1 : 0;  // 1 = int64 edges
}

// ---------------- params -> canonical fp32 copies ----------------
struct PP {
  const void* src[14];
  int off[14];
  int cnt[14];
};

__global__ void cvt_params_kernel(PP pp, float* __restrict__ dst, const int* __restrict__ flag){
  int b = blockIdx.x;
  int cnt = pp.cnt[b];
  float* d = dst + pp.off[b];
  if (flag[0] != 0){
    const float* s = (const float*)pp.src[b];
    for (int i = threadIdx.x; i < cnt; i += 256) d[i] = s[i];
  } else {
    const uint16_t* s = (const uint16_t*)pp.src[b];
    for (int i = threadIdx.x; i < cnt; i += 256) d[i] = us2f(s[i]);
  }
}

// ---------------- CSR build ----------------
__global__ void count_kernel(const int* __restrict__ ei, const int* __restrict__ eflag,
                             int* __restrict__ counts, int E, int n){
  int i = blockIdx.x * 256 + threadIdx.x;
  if (i >= E + n) return;
  int d;
  if (i < E) d = eflag[0] ? ei[2*(size_t)E + 2*(size_t)i] : ei[(size_t)E + i];
  else       d = i - E;
  atomicAdd(&counts[d], 1);
}

#define SCAN_BS 256
#define SCAN_CHUNK 1024

__global__ void scan1_kernel(const int* __restrict__ counts, int* __restrict__ offs,
                             int* __restrict__ bsums, int n){
  __shared__ int sdata[SCAN_BS];
  int b = blockIdx.x, t = threadIdx.x;
  int base = b * SCAN_CHUNK + t * 4;
  int v[4]; int s = 0;
  #pragma unroll
  for (int j=0;j<4;j++){ int idx = base+j; v[j] = (idx<n)? counts[idx] : 0; s += v[j]; }
  sdata[t] = s;
  __syncthreads();
  for (int off=1; off<SCAN_BS; off<<=1){
    int x = (t>=off)? sdata[t-off] : 0;
    __syncthreads();
    sdata[t] += x;
    __syncthreads();
  }
  int run = sdata[t] - s;
  #pragma unroll
  for (int j=0;j<4;j++){ int idx = base+j; if (idx<n) offs[idx] = run; run += v[j]; }
  if (t == SCAN_BS-1) bsums[b] = sdata[t];
}

__global__ void scan2_kernel(int* __restrict__ bsums, int nb){
  __shared__ int sdata[1024];
  int t = threadIdx.x;
  int v = (t<nb)? bsums[t] : 0;
  sdata[t] = v;
  __syncthreads();
  for (int off=1; off<1024; off<<=1){
    int x = (t>=off)? sdata[t-off] : 0;
    __syncthreads();
    sdata[t] += x;
    __syncthreads();
  }
  if (t<nb) bsums[t] = sdata[t] - v;
}

__global__ void scan3_kernel(int* __restrict__ offs, const int* __restrict__ bsums,
                             int* __restrict__ cursor, int n, int total){
  int i = blockIdx.x * 256 + threadIdx.x;
  if (i < n){
    int v = offs[i] + bsums[i / SCAN_CHUNK];
    offs[i] = v;
    cursor[i] = v;
  }
  if (i == n) offs[n] = total;
}

__global__ void fill_kernel(const int* __restrict__ ei, const int* __restrict__ eflag,
                            int* __restrict__ cursor, int* __restrict__ csr, int E, int n){
  int i = blockIdx.x * 256 + threadIdx.x;
  if (i >= E + n) return;
  int s, d;
  if (i < E){
    if (eflag[0]){ s = ei[2*(size_t)i]; d = ei[2*(size_t)E + 2*(size_t)i]; }
    else         { s = ei[i];           d = ei[(size_t)E + i]; }
  } else { s = i - E; d = i - E; }
  int pos = atomicAdd(&cursor[d], 1);
  csr[pos] = s;
}

// ---- GEMM v2: C[n,M] = A[n,K] @ W[K,M], both staged in LDS, no shfl ----
// Block: BR=8192/M rows x M cols. Thread: 4 rows x 8 contiguous cols (32 acc).
// LDS: As[BR][65] (pad -> conflict-free) + Ws[64][M]; ~49 KB -> 3 blocks/CU.
template<int K, int M, bool DET, typename TA, typename TC>
__global__ __launch_bounds__(256) void gemm_kernel(const void* __restrict__ Ap,
    const float* __restrict__ W, TC* __restrict__ C, int n, const int* __restrict__ flag){
  constexpr int TX = M/8;        // col groups per block
  constexpr int BR = 1024/TX;    // rows per block (M=128->64, M=64->128)
  constexpr int KC = K/64;
  __shared__ float As[BR*65];
  __shared__ float Ws[64*M];
  int tid = threadIdx.x;
  int tx = tid % TX;             // col group: cols tx*8..tx*8+7
  int ty = tid / TX;             // row group: rows ty*4..ty*4+3
  int r0b = blockIdx.x * BR;

  bool f32 = DET ? (flag[0] != 0) : false;
  const uint16_t* Au = (const uint16_t*)Ap;
  const float*    Af = (const float*)Ap;
  const TA*       At = (const TA*)Ap;

  float acc[4][8];
  #pragma unroll
  for (int r=0;r<4;r++)
    #pragma unroll
    for (int j=0;j<8;j++) acc[r][j] = 0.f;

  for (int c=0; c<KC; c++){
    // stage W chunk (64 x M), coalesced float4
    const float4* Wg = (const float4*)(W + (size_t)c*64*M);
    for (int i=tid; i < 64*M/4; i += 256) ((float4*)Ws)[i] = Wg[i];
    // stage A chunk (BR x 64), coalesced within rows, padded stride 65
    for (int i=tid; i < BR*64; i += 256){
      int r = i >> 6, k = i & 63;
      int gr = r0b + r;
      float a = 0.f;
      if (gr < n){
        size_t idx = (size_t)gr*K + c*64 + k;
        if (DET) a = f32 ? Af[idx] : us2f(Au[idx]);
        else     a = ldh(At, idx);
      }
      As[r*65 + k] = a;
    }
    __syncthreads();
    #pragma unroll 8
    for (int k2=0; k2<64; k2++){
      float a0 = As[(ty*4+0)*65 + k2];
      float a1 = As[(ty*4+1)*65 + k2];
      float a2 = As[(ty*4+2)*65 + k2];
      float a3 = As[(ty*4+3)*65 + k2];
      float w[8];
      #pragma unroll
      for (int j=0;j<8;j++) w[j] = Ws[k2*M + tx*8 + j];
      #pragma unroll
      for (int j=0;j<8;j++){
        acc[0][j] = fmaf(a0, w[j], acc[0][j]);
        acc[1][j] = fmaf(a1, w[j], acc[1][j]);
        acc[2][j] = fmaf(a2, w[j], acc[2][j]);
        acc[3][j] = fmaf(a3, w[j], acc[3][j]);
      }
    }
    __syncthreads();
  }
  #pragma unroll
  for (int r=0;r<4;r++){
    int gr = r0b + ty*4 + r;
    if (gr < n){
      #pragma unroll
      for (int j=0;j<8;j++)
        sth(C, (size_t)gr*M + tx*8 + j, acc[r][j]);
    }
  }
}

// ---------------- per-node attention logits ----------------
template<int OUTD, int HD, typename T>
__global__ void logits_kernel(const T* __restrict__ hW, const float* __restrict__ a_src,
                              const float* __restrict__ a_dst, float* __restrict__ als,
                              float* __restrict__ ald, int n){
  int i = blockIdx.x * 256 + threadIdx.x;   // i = node*4 + h
  if (i >= n*4) return;
  int node = i >> 2, h = i & 3;
  const T* hp = hW + (size_t)node*OUTD + h*HD;
  float ss = 0.f, sd = 0.f;
  #pragma unroll
  for (int d2=0; d2<HD/2; d2++){
    float2 v = ldh2(hp, d2);
    int b = h*HD + 2*d2;
    ss += v.x*a_src[b] + v.y*a_src[b+1];
    sd += v.x*a_dst[b] + v.y*a_dst[b+1];
  }
  als[i] = ss; ald[i] = sd;
}

// ---------------- aggregation: one wave per destination node ----------------
template<int OUTD, typename TIN, typename TOUT>
__global__ __launch_bounds__(256) void aggregate_kernel(const TIN* __restrict__ hW,
            const float* __restrict__ als, const float* __restrict__ ald,
            const int* __restrict__ offs, const int* __restrict__ csr,
            const float* __restrict__ bias, TOUT* __restrict__ hout, int n){
  int wid = (blockIdx.x * 256 + threadIdx.x) >> 6;   // node
  if (wid >= n) return;
  int lane = threadIdx.x & 63;
  int beg = offs[wid], end = offs[wid+1];
  const float4 ad = ((const float4*)ald)[wid];

  // pass A: per-head segment max (lanes parallel over edges)
  float m0=-1e30f, m1=-1e30f, m2=-1e30f, m3=-1e30f;
  for (int j = beg + lane; j < end; j += 64){
    int s = csr[j];
    float4 as = ((const float4*)als)[s];
    float e;
    e = as.x + ad.x; e = (e>0.f)? e : 0.2f*e; m0 = fmaxf(m0, e);
    e = as.y + ad.y; e = (e>0.f)? e : 0.2f*e; m1 = fmaxf(m1, e);
    e = as.z + ad.z; e = (e>0.f)? e : 0.2f*e; m2 = fmaxf(m2, e);
    e = as.w + ad.w; e = (e>0.f)? e : 0.2f*e; m3 = fmaxf(m3, e);
  }
  #pragma unroll
  for (int off=32; off>0; off>>=1){
    m0 = fmaxf(m0, __shfl_xor(m0, off));
    m1 = fmaxf(m1, __shfl_xor(m1, off));
    m2 = fmaxf(m2, __shfl_xor(m2, off));
    m3 = fmaxf(m3, __shfl_xor(m3, off));
  }

  int h = lane >> 4;
  float mh  = (h==0)? m0 : (h==1)? m1 : (h==2)? m2 : m3;
  float adh = (h==0)? ad.x : (h==1)? ad.y : (h==2)? ad.z : ad.w;

  if (OUTD == 128){
    float acc0 = 0.f, acc1 = 0.f, den = 0.f;
    for (int j=beg; j<end; j++){
      int s = csr[j];
      float e = als[s*4 + h] + adh;
      e = (e>0.f)? e : 0.2f*e;
      float ex = __expf(e - mh);
      den += ex;
      float2 hv = ldh2(hW, (size_t)s*64 + lane);
      acc0 = fmaf(ex, hv.x, acc0);
      acc1 = fmaf(ex, hv.y, acc1);
    }
    float inv = 1.f / (den + 1e-16f);
    float o0 = acc0*inv + bias[2*lane];
    float o1 = acc1*inv + bias[2*lane+1];
    o0 = (o0>0.f)? o0 : 0.f;
    o1 = (o1>0.f)? o1 : 0.f;
    sth2(hout, (size_t)wid*64 + lane, make_float2(o0, o1));
  } else {
    float acc0 = 0.f, den = 0.f;
    for (int j=beg; j<end; j++){
      int s = csr[j];
      float e = als[s*4 + h] + adh;
      e = (e>0.f)? e : 0.2f*e;
      float ex = __expf(e - mh);
      den += ex;
      acc0 = fmaf(ex, ldh(hW, (size_t)s*OUTD + lane), acc0);
    }
    float o0 = acc0 / (den + 1e-16f) + bias[lane];
    o0 = (o0>0.f)? o0 : 0.f;
    sth(hout, (size_t)wid*OUTD + lane, o0);
  }
}

// ---------- classifier: out[n,40] = h[n,64] @ Wc + bc  (fp32 output) ----------
template<typename T>
__global__ __launch_bounds__(256) void classifier_kernel(const T* __restrict__ h,
      const float* __restrict__ Wc, const float* __restrict__ bc,
      float* __restrict__ out, int n){
  __shared__ float Ws[64*40 + 64];
  __shared__ float bs[40];
  int t = threadIdx.x;
  for (int i=t; i<64*40; i+=256) Ws[i] = Wc[i];
  if (t < 40) bs[t] = bc[t];
  for (int i = 64*40 + t; i < 64*40 + 64; i += 256) Ws[i] = 0.f; // pad
  __syncthreads();
  int wid = blockIdx.x * 4 + (t >> 6);
  if (wid >= n) return;
  int lane = t & 63;
  float a = ldh(h, (size_t)wid*64 + lane);
  float acc = 0.f;
  #pragma unroll
  for (int k=0;k<64;k++){
    float ak = __shfl(a, k);
    acc = fmaf(ak, Ws[k*40 + lane], acc);  // lanes >=40 hit pad (harmless)
  }
  if (lane < 40) out[(size_t)wid*40 + lane] = acc + bs[lane];
}

// ---------------- pipeline ----------------
template<typename TM, typename TO>
static void run_pipeline(void* const* d_in, int ei_idx, int pbase, int n, int E,
                         void* d_out, int out_size, void* d_ws, size_t ws_size,
                         hipStream_t stream){
  const void* x = d_in[0];
  const int* ei = (const int*)d_in[ei_idx];
  float* out = (float*)d_out;           // fp32 output (R8 sentinel evidence)
  int Etot = E + n;

  char* p = (char*)d_ws;
  auto alloc = [&](size_t bytes)->char* {
    char* r = p; p += (bytes + 255) & ~(size_t)255; return r;
  };
  int*   flag   = (int*)  alloc(256);
  int*   eflag  = (int*)  alloc(256);
  int*   counts = (int*)  alloc((size_t)n * 4);
  float* als    = (float*)alloc((size_t)n * 16);
  float* ald    = (float*)alloc((size_t)n * 16);
  float* prm    = (float*)alloc(48000 * 4);
  int*   cursor = counts;

  // csr/offs/bsums in d_out (fp32 out: 16 MB; dead until classifier overwrite)
  size_t csr_b  = ((size_t)Etot * 4 + 255) & ~(size_t)255;
  size_t offs_b = ((size_t)(n + 1) * 4 + 255) & ~(size_t)255;
  size_t out_bytes = (size_t)out_size * 4;
  int *csr, *offs, *bsums;
  if (csr_b + offs_b + 4096 <= out_bytes){
    char* q = (char*)d_out;
    csr   = (int*)q;
    offs  = (int*)(q + csr_b);
    bsums = (int*)(q + csr_b + offs_b);
  } else {
    csr   = (int*)alloc((size_t)Etot * 4);
    offs  = (int*)alloc((size_t)(n + 1) * 4);
    bsums = (int*)alloc(4096);
  }
  TM* bufMid = (TM*)alloc((size_t)n * 128 * sizeof(TM));
  TO* bufOut = (TO*)alloc((size_t)n * 128 * sizeof(TO));

  PP pp;
  static const int cnts[14] = {16384,128,128,128, 16384,128,128,128, 8192,64,64,64, 2560,40};
  int off = 0;
  for (int i = 0; i < 14; i++){
    pp.src[i] = d_in[pbase + i];
    pp.cnt[i] = cnts[i];
    pp.off[i] = off;
    off += cnts[i];
  }
  const float* W0  = prm + pp.off[0];
  const float* as0 = prm + pp.off[1];
  const float* ad0 = prm + pp.off[2];
  const float* b0  = prm + pp.off[3];
  const float* W1  = prm + pp.off[4];
  const float* as1 = prm + pp.off[5];
  const float* ad1 = prm + pp.off[6];
  const float* b1  = prm + pp.off[7];
  const float* W2  = prm + pp.off[8];
  const float* as2 = prm + pp.off[9];
  const float* ad2 = prm + pp.off[10];
  const float* b2  = prm + pp.off[11];
  const float* Wc  = prm + pp.off[12];
  const float* bc  = prm + pp.off[13];

  hipMemsetAsync(counts, 0, (size_t)n * 4, stream);

  detect_kernel<<<1, 64, 0, stream>>>((const uint32_t*)x, flag);
  edetect_kernel<<<1, 64, 0, stream>>>((const uint32_t*)ei, eflag);
  cvt_params_kernel<<<14, 256, 0, stream>>>(pp, prm, flag);

  count_kernel<<<(Etot + 255)/256, 256, 0, stream>>>(ei, eflag, counts, E, n);
  int nb = (n + SCAN_CHUNK - 1) / SCAN_CHUNK;
  scan1_kernel<<<nb, SCAN_BS, 0, stream>>>(counts, offs, bsums, n);
  scan2_kernel<<<1, 1024, 0, stream>>>(bsums, nb);
  scan3_kernel<<<(n + 1 + 255)/256, 256, 0, stream>>>(offs, bsums, cursor, n, Etot);
  fill_kernel<<<(Etot + 255)/256, 256, 0, stream>>>(ei, eflag, cursor, csr, E, n);

  int g128 = (n + 63) / 64;      // gemm M=128: BR=64
  int g64  = (n + 127) / 128;    // gemm M=64:  BR=128
  int log_grid = (n*4 + 255) / 256;
  int agg_grid = (n + 3) / 4;

  // layer 0: x -> bufMid -> bufOut   (x dtype runtime-detected; expect fp32)
  gemm_kernel<128,128,true,TO,TM><<<g128, 256, 0, stream>>>(x, W0, bufMid, n, flag);
  logits_kernel<128,32,TM><<<log_grid, 256, 0, stream>>>(bufMid, as0, ad0, als, ald, n);
  aggregate_kernel<128,TM,TO><<<agg_grid, 256, 0, stream>>>(bufMid, als, ald, offs, csr, b0, bufOut, n);

  // layer 1
  gemm_kernel<128,128,false,TO,TM><<<g128, 256, 0, stream>>>(bufOut, W1, bufMid, n, flag);
  logits_kernel<128,32,TM><<<log_grid, 256, 0, stream>>>(bufMid, as1, ad1, als, ald, n);
  aggregate_kernel<128,TM,TO><<<agg_grid, 256, 0, stream>>>(bufMid, als, ald, offs, csr, b1, bufOut, n);

  // layer 2 (outd=64)
  gemm_kernel<128,64,false,TO,TM><<<g64, 256, 0, stream>>>(bufOut, W2, bufMid, n, flag);
  logits_kernel<64,16,TM><<<log_grid, 256, 0, stream>>>(bufMid, as2, ad2, als, ald, n);
  aggregate_kernel<64,TM,TO><<<agg_grid, 256, 0, stream>>>(bufMid, als, ald, offs, csr, b2, bufOut, n);

  // classifier: fp32 writes, fully overwrites d_out
  classifier_kernel<TO><<<agg_grid, 256, 0, stream>>>(bufOut, Wc, bc, out, n);
}

// ---------------- launcher ----------------
extern "C" void kernel_launch(void* const* d_in, const int* in_sizes, int n_in,
                              void* d_out, int out_size, void* d_ws, size_t ws_size,
                              hipStream_t stream) {
  int n = in_sizes[0] / 128;

  int ei_idx, pbase;
  if (n_in >= 2 && in_sizes[1] > 1000000) { ei_idx = 1;        pbase = 2; }   // dict order
  else                                    { ei_idx = n_in - 1; pbase = 1; }   // signature order
  int E = in_sizes[ei_idx] / 2;

  size_t base = 512
              + (((size_t)n*4  + 255) & ~(size_t)255)
              + 2*(((size_t)n*16 + 255) & ~(size_t)255)
              + ((48000*4 + 255) & ~(size_t)255)
              + 65536;
  size_t f32buf  = ((size_t)n*128*4 + 255) & ~(size_t)255;
  size_t bf16buf = ((size_t)n*128*2 + 255) & ~(size_t)255;

  if (ws_size >= base + 2*f32buf)              // tier 1: all fp32
    run_pipeline<float, float>(d_in, ei_idx, pbase, n, E, d_out, out_size, d_ws, ws_size, stream);
  else if (ws_size >= base + f32buf + bf16buf) // tier 2: fp32 gather buf, bf16 h
    run_pipeline<float, uint16_t>(d_in, ei_idx, pbase, n, E, d_out, out_size, d_ws, ws_size, stream);
  else                                         // tier 3: all bf16
    run_pipeline<uint16_t, uint16_t>(d_in, ei_idx, pbase, n, E, d_out, out_size, d_ws, ws_size, stream);
}